// Round 5
// baseline (190.336 us; speedup 1.0000x reference)
//
#include <hip/hip_runtime.h>
#include <hip/hip_bf16.h>
#include <math.h>

// KAN layer: out = GELU( einsum('bik,ikj->bj', x^k, W) + bias ),
//   B=4096, D=1024, K=5, U=1024.
//
// Round 5: hybrid GEMM (K=4096, k=0 plane folded into bias via partials):
//  - B operand pre-packed in MFMA fragment order (1 KB units: 16 cols x 32 k;
//    lane l holds col l&15, k-octet l>>4), DMA'd global->LDS (dbuf, one
//    barrier/iter), read back as single ds_read_b128 fragments.
//  - A operand never materialized: each lane loads float2 of x and builds the
//    bf16 power fragment in registers (VALU co-issues under MFMA shadow).
//  - 2 kernels total: w_pack_fold (pack B + k=0 partial sums) and gemm
//    (epilogue sums partials + bias, applies exact GELU).

#define B_DIM 4096
#define D_DIM 1024
#define U_DIM 1024
#define KT2 4096            // GEMM K after dropping k=0 plane
#define NKB 128             // 32-wide k-blocks

typedef unsigned short ushort_t;
typedef __attribute__((ext_vector_type(8))) short bf16x8;   // MFMA A/B frag
typedef __attribute__((ext_vector_type(4))) float f32x4;    // MFMA C/D frag

__device__ __forceinline__ ushort_t f2bf(float f) {   // RNE
  union { float f; unsigned int u; } v;
  v.f = f;
  unsigned int r = v.u + 0x7FFFu + ((v.u >> 16) & 1u);
  return (ushort_t)(r >> 16);
}

__device__ __forceinline__ void load_lds16(const ushort_t* g, ushort_t* l) {
  __builtin_amdgcn_global_load_lds(
      (const __attribute__((address_space(1))) ushort_t*)g,
      (__attribute__((address_space(3))) ushort_t*)l, 16, 0, 0);
}

__device__ __forceinline__ float gelu_exact(float v) {
  return 0.5f * v * (1.0f + erff(v * 0.70710678118654752f));
}

// A-fragment from two x values: 8 bf16 = {xa,xa^2,xa^3,xa^4, xb,xb^2,xb^3,xb^4}
// (round-half-away pack, |err| <= ulp/2)
__device__ __forceinline__ bf16x8 build_afrag(float xa, float xb) {
  const float a2 = xa * xa, b2 = xb * xb;
  float p[8] = {xa, a2, a2 * xa, a2 * a2, xb, b2, b2 * xb, b2 * b2};
  union { bf16x8 v; unsigned int d[4]; } r;
#pragma unroll
  for (int i = 0; i < 4; ++i) {
    union { float f; unsigned int u; } lo, hi;
    lo.f = p[2 * i];
    hi.f = p[2 * i + 1];
    const unsigned int ul = lo.u + 0x8000u;
    const unsigned int uh = hi.u + 0x8000u;
    r.d[i] = (ul >> 16) | (uh & 0xFFFF0000u);
  }
  return r.v;
}

// packed addr (ushorts) of (row=j, k): ((j>>4)*NKB + (k>>5))*512
//                                       + (((k>>3)&3)*16 + (j&15))*8 + (k&7)

// ---------------- prep: pack W planes 1..4 + partial sums of plane 0 ----------------
// grid (32, 64): block (bx, n16) covers i in [bx*32, bx*32+32), j in [n16*16, +16).
__global__ __launch_bounds__(256) void w_pack_fold_kernel(
    const float* __restrict__ W, ushort_t* __restrict__ Bp, float* __restrict__ part) {
  const int t    = threadIdx.x;
  const int wave = t >> 6;
  const int lane = t & 63;
  const int bx   = blockIdx.x;                // 0..31
  const int n16  = blockIdx.y;                // 0..63
  // ---- pack: 4 waves, each one (kblk, n16) unit ----
  {
    const int kblk = bx * 4 + wave;           // 0..127
    const int jj   = lane & 15;
    const int ko   = lane >> 4;
    const int j    = n16 * 16 + jj;
    const int i0   = kblk * 8 + ko * 2;
    ushort_t o[8];
#pragma unroll
    for (int t2 = 0; t2 < 2; ++t2) {
      const int i = i0 + t2;
#pragma unroll
      for (int e = 0; e < 4; ++e) {
        const int r = i * 5 + e + 1;          // skip k=0 plane
        o[t2 * 4 + e] = f2bf(W[(size_t)r * U_DIM + j]);
      }
    }
    *(uint4*)(Bp + ((size_t)n16 * NKB + kblk) * 512 + lane * 8) = *(const uint4*)o;
  }
  // ---- fold: partial sum over this block's 32 i of W[i,0,j] ----
  __shared__ float red[16][17];
  {
    const int jj = t & 15;
    const int ii = t >> 4;                    // 0..15, covers 2 i's
    const int i1 = bx * 32 + ii;
    const int i2 = i1 + 16;
    const int j  = n16 * 16 + jj;
    red[ii][jj] = W[(size_t)(i1 * 5) * U_DIM + j] + W[(size_t)(i2 * 5) * U_DIM + j];
  }
  __syncthreads();
  if (t < 16) {
    float s = 0.0f;
#pragma unroll
    for (int ii = 0; ii < 16; ++ii) s += red[ii][t];
    part[(size_t)bx * U_DIM + n16 * 16 + t] = s;
  }
}

// ---------------- main GEMM: 128x128 tile, B via dbuf LDS DMA, A in regs ----------------
// wave tile 64x64 (4x4 of 16x16x32). BK=64 (2 k32-blocks per iter).
__global__ __launch_bounds__(256) void gemm_kernel(
    const float* __restrict__ x, const ushort_t* __restrict__ Bp,
    const float* __restrict__ bias, const float* __restrict__ part,
    float* __restrict__ C) {
  __shared__ ushort_t lds[2][16 * 512];   // 2 x 16 KB (unit u = kloc*8 + n16loc)

  const int tid  = threadIdx.x;
  const int wave = tid >> 6;
  const int lane = tid & 63;
  const int wm   = wave >> 1;             // 0..1
  const int wn   = wave & 1;              // 0..1
  const int tileM = blockIdx.y * 128;
  const int tileN = blockIdx.x * 128;

  // DMA staging: wave stages units u = wave*4+s (s=0..3); u = kloc*8 + nloc
  const ushort_t* gsrc[4];
  int ldst[4];
#pragma unroll
  for (int s = 0; s < 4; ++s) {
    const int u    = wave * 4 + s;
    const int nloc = u & 7;
    const int kloc = u >> 3;
    gsrc[s] = Bp + ((size_t)((tileN >> 4) + nloc) * NKB + kloc) * 512 + lane * 8;
    ldst[s] = u * 512 + lane * 8;
  }

  // x pointers: frag mf covers rows tileM + wm*64 + mf*16 + (lane&15);
  // k-octet (lane>>4) -> i-pair base (lane>>4)*2 within each k32 block.
  const float* xptr[4];
#pragma unroll
  for (int mf = 0; mf < 4; ++mf)
    xptr[mf] = x + (size_t)(tileM + wm * 64 + mf * 16 + (lane & 15)) * D_DIM
                 + (lane >> 4) * 2;

  f32x4 acc[4][4];
  const f32x4 zero = {0.0f, 0.0f, 0.0f, 0.0f};
#pragma unroll
  for (int mf = 0; mf < 4; ++mf)
#pragma unroll
    for (int nf = 0; nf < 4; ++nf) acc[mf][nf] = zero;

#define STAGE(bb, it)                                                   \
  do {                                                                  \
    _Pragma("unroll")                                                   \
    for (int s = 0; s < 4; ++s)                                         \
      load_lds16(gsrc[s] + (size_t)(it) * 1024, &lds[bb][ldst[s]]);     \
  } while (0)

  // x prefetch for iter 0 (2 k32 blocks x 4 mf)
  float2 xc[2][4], xn[2][4];
#pragma unroll
  for (int kl = 0; kl < 2; ++kl)
#pragma unroll
    for (int mf = 0; mf < 4; ++mf)
      xc[kl][mf] = *(const float2*)(xptr[mf] + (size_t)kl * 8);

  STAGE(0, 0);
  __syncthreads();   // drain iter-0 DMA

  for (int it = 0; it < 64; ++it) {
    const int cur = it & 1;
    if (it + 1 < 64) {
      STAGE(cur ^ 1, it + 1);   // in flight across this iter's compute
#pragma unroll
      for (int kl = 0; kl < 2; ++kl)
#pragma unroll
        for (int mf = 0; mf < 4; ++mf)
          xn[kl][mf] = *(const float2*)(xptr[mf] + ((size_t)(it + 1) * 2 + kl) * 8);
    }

#pragma unroll
    for (int kl = 0; kl < 2; ++kl) {
      bf16x8 a[4], b[4];
#pragma unroll
      for (int mf = 0; mf < 4; ++mf)
        a[mf] = build_afrag(xc[kl][mf].x, xc[kl][mf].y);
#pragma unroll
      for (int nf = 0; nf < 4; ++nf)
        b[nf] = *(const bf16x8*)&lds[cur][(kl * 8 + wn * 4 + nf) * 512 + lane * 8];
#pragma unroll
      for (int mf = 0; mf < 4; ++mf)
#pragma unroll
        for (int nf = 0; nf < 4; ++nf)
          acc[mf][nf] = __builtin_amdgcn_mfma_f32_16x16x32_bf16(a[mf], b[nf], acc[mf][nf], 0, 0, 0);
    }

#pragma unroll
    for (int kl = 0; kl < 2; ++kl)
#pragma unroll
      for (int mf = 0; mf < 4; ++mf)
        xc[kl][mf] = xn[kl][mf];

    __syncthreads();   // releases cur for overwrite; drains next-iter DMA
  }
#undef STAGE

  // epilogue: C/D map: col = lane&15, row = (lane>>4)*4 + reg
  const int crow0 = tileM + wm * 64 + (lane >> 4) * 4;
  const int ccol0 = tileN + wn * 64 + (lane & 15);
#pragma unroll
  for (int nf = 0; nf < 4; ++nf) {
    const int col = ccol0 + nf * 16;
    float bv = bias[col];
#pragma unroll 8
    for (int g = 0; g < 32; ++g) bv += part[(size_t)g * U_DIM + col];
#pragma unroll
    for (int mf = 0; mf < 4; ++mf) {
#pragma unroll
      for (int r = 0; r < 4; ++r) {
        const int row = crow0 + mf * 16 + r;
        C[(size_t)row * U_DIM + col] = gelu_exact(acc[mf][nf][r] + bv);
      }
    }
  }
}

// ---------------- fallback (ws too small): fp32, no workspace ----------------
__global__ void fallback_kernel(const float* __restrict__ x, const float* __restrict__ W,
                                const float* __restrict__ bias, float* __restrict__ out) {
  int j  = blockIdx.x * 256 + threadIdx.x;
  int b0 = blockIdx.y * 16;
  float acc[16];
#pragma unroll
  for (int t = 0; t < 16; ++t) acc[t] = 0.0f;
  for (int i = 0; i < D_DIM; ++i) {
    const float* wr = W + (size_t)i * 5 * U_DIM + j;
    float w0 = wr[0 * U_DIM], w1 = wr[1 * U_DIM], w2 = wr[2 * U_DIM];
    float w3 = wr[3 * U_DIM], w4 = wr[4 * U_DIM];
#pragma unroll
    for (int t = 0; t < 16; ++t) {
      float xv = x[(size_t)(b0 + t) * D_DIM + i];
      float x2 = xv * xv;
      acc[t] += w0 + xv * w1 + x2 * w2 + x2 * xv * w3 + x2 * x2 * w4;
    }
  }
  float bv = bias[j];
#pragma unroll
  for (int t = 0; t < 16; ++t)
    out[(size_t)(b0 + t) * U_DIM + j] = gelu_exact(acc[t] + bv);
}

extern "C" void kernel_launch(void* const* d_in, const int* in_sizes, int n_in,
                              void* d_out, int out_size, void* d_ws, size_t ws_size,
                              hipStream_t stream) {
  const float* x    = (const float*)d_in[0];   // (4096, 1024)
  const float* W    = (const float*)d_in[1];   // (1024, 5, 1024), row r = i*5+k
  const float* bias = (const float*)d_in[2];   // (1024,)
  float* out = (float*)d_out;                  // (4096, 1024) fp32

  const size_t szB = (size_t)U_DIM * KT2 * sizeof(ushort_t);   // 8.39 MB
  const size_t szP = (size_t)32 * U_DIM * sizeof(float);       // 128 KB

  if (ws_size >= szB + szP) {
    ushort_t* Bp   = (ushort_t*)d_ws;
    float*    part = (float*)((char*)d_ws + szB);
    w_pack_fold_kernel<<<dim3(32, U_DIM / 16), 256, 0, stream>>>(W, Bp, part);
    gemm_kernel<<<dim3(U_DIM / 128, B_DIM / 128), 256, 0, stream>>>(x, Bp, bias, part, out);
  } else {
    fallback_kernel<<<dim3(U_DIM / 256, B_DIM / 16), 256, 0, stream>>>(x, W, bias, out);
  }
}

// Round 6
// 162.944 us; speedup vs baseline: 1.1681x; 1.1681x over previous
//
#include <hip/hip_runtime.h>
#include <hip/hip_bf16.h>
#include <math.h>

// KAN layer: out = GELU( einsum('bik,ikj->bj', x^k, W) + bias ),
//   B=4096, D=1024, K=5, U=1024.
//
// Round 6 = R3's occupancy x R5's hybrid:
//  - GEMM K=4096 (k=0 plane folded into bias via partials).
//  - 64x128 tile -> grid (8,64)=512 blocks = 2-3 blocks/CU (the variable that
//    separated 52us from 119us across R2-R5: a co-resident block covers the
//    pre-barrier vmcnt drain).
//  - B pre-packed in MFMA fragment order (1 KB units), DMA'd global->LDS,
//    double-buffered, one barrier/iter (BK=64).
//  - A never materialized: lane loads float2 of x, builds bf16 power-frag in
//    registers. Pack via v_perm_b32 (1 instr per f32 pair, truncation) so the
//    build is ~10 VALU and hides under the MFMA shadow.

#define B_DIM 4096
#define D_DIM 1024
#define U_DIM 1024
#define KT2 4096            // GEMM K after dropping k=0 plane
#define NKB 128             // 32-wide k-blocks

typedef unsigned short ushort_t;
typedef __attribute__((ext_vector_type(8))) short bf16x8;   // MFMA A/B frag
typedef __attribute__((ext_vector_type(4))) float f32x4;    // MFMA C/D frag

__device__ __forceinline__ ushort_t f2bf(float f) {   // RNE (prep kernel)
  union { float f; unsigned int u; } v;
  v.f = f;
  unsigned int r = v.u + 0x7FFFu + ((v.u >> 16) & 1u);
  return (ushort_t)(r >> 16);
}

__device__ __forceinline__ void load_lds16(const ushort_t* g, ushort_t* l) {
  __builtin_amdgcn_global_load_lds(
      (const __attribute__((address_space(1))) ushort_t*)g,
      (__attribute__((address_space(3))) ushort_t*)l, 16, 0, 0);
}

__device__ __forceinline__ float gelu_exact(float v) {
  return 0.5f * v * (1.0f + erff(v * 0.70710678118654752f));
}

__device__ __forceinline__ unsigned int fbits(float f) {
  union { float f; unsigned int u; } v; v.f = f; return v.u;
}

// A-frag: 8 bf16 = {xa,xa^2,xa^3,xa^4, xb,xb^2,xb^3,xb^4}.
// v_perm_b32 packs the two f32 high-halves in ONE instr (truncation: |err|<=ulp,
// vs ulp/2 for RNE; W signs are random so dot-error stays a random walk).
__device__ __forceinline__ bf16x8 build_afrag(float xa, float xb) {
  const float a2 = xa * xa, b2 = xb * xb;
  const float a3 = a2 * xa, a4 = a2 * a2;
  const float b3 = b2 * xb, b4 = b2 * b2;
  union { bf16x8 v; unsigned int d[4]; } r;
  r.d[0] = __builtin_amdgcn_perm(fbits(a2), fbits(xa), 0x07060302u);  // {a2|xa}
  r.d[1] = __builtin_amdgcn_perm(fbits(a4), fbits(a3), 0x07060302u);  // {a4|a3}
  r.d[2] = __builtin_amdgcn_perm(fbits(b2), fbits(xb), 0x07060302u);
  r.d[3] = __builtin_amdgcn_perm(fbits(b4), fbits(b3), 0x07060302u);
  return r.v;
}

// packed addr (ushorts) of (row=j, k): ((j>>4)*NKB + (k>>5))*512
//                                       + (((k>>3)&3)*16 + (j&15))*8 + (k&7)

// ---------------- prep: pack W planes 1..4 + partial sums of plane 0 ----------------
__global__ __launch_bounds__(256) void w_pack_fold_kernel(
    const float* __restrict__ W, ushort_t* __restrict__ Bp, float* __restrict__ part) {
  const int t    = threadIdx.x;
  const int wave = t >> 6;
  const int lane = t & 63;
  const int bx   = blockIdx.x;                // 0..31
  const int n16  = blockIdx.y;                // 0..63
  {
    const int kblk = bx * 4 + wave;           // 0..127
    const int jj   = lane & 15;
    const int ko   = lane >> 4;
    const int j    = n16 * 16 + jj;
    const int i0   = kblk * 8 + ko * 2;
    ushort_t o[8];
#pragma unroll
    for (int t2 = 0; t2 < 2; ++t2) {
      const int i = i0 + t2;
#pragma unroll
      for (int e = 0; e < 4; ++e) {
        const int r = i * 5 + e + 1;          // skip k=0 plane
        o[t2 * 4 + e] = f2bf(W[(size_t)r * U_DIM + j]);
      }
    }
    *(uint4*)(Bp + ((size_t)n16 * NKB + kblk) * 512 + lane * 8) = *(const uint4*)o;
  }
  __shared__ float red[16][17];
  {
    const int jj = t & 15;
    const int ii = t >> 4;                    // 0..15, covers 2 i's
    const int i1 = bx * 32 + ii;
    const int i2 = i1 + 16;
    const int j  = n16 * 16 + jj;
    red[ii][jj] = W[(size_t)(i1 * 5) * U_DIM + j] + W[(size_t)(i2 * 5) * U_DIM + j];
  }
  __syncthreads();
  if (t < 16) {
    float s = 0.0f;
#pragma unroll
    for (int ii = 0; ii < 16; ++ii) s += red[ii][t];
    part[(size_t)bx * U_DIM + n16 * 16 + t] = s;
  }
}

// ---------------- main GEMM: 64x128 tile, B via dbuf LDS DMA, A in regs ----------------
// 4 waves: wave tile 32x64 (2x4 of 16x16x32). BK=64 (2 k32-blocks/iter).
__global__ __launch_bounds__(256, 2) void gemm_kernel(
    const float* __restrict__ x, const ushort_t* __restrict__ Bp,
    const float* __restrict__ bias, const float* __restrict__ part,
    float* __restrict__ C) {
  __shared__ ushort_t lds[2][16 * 512];   // 2 x 16 KB; unit u = kloc*8 + nloc

  const int tid  = threadIdx.x;
  const int wave = tid >> 6;
  const int lane = tid & 63;
  const int wm   = wave >> 1;             // 0..1 : 32-row half
  const int wn   = wave & 1;              // 0..1 : 64-col half
  const int tileN = blockIdx.x * 128;     // 8 n-tiles (XCD round-robin)
  const int tileM = blockIdx.y * 64;      // 64 m-tiles

  // DMA staging: wave stages units u = wave*4+s; u = kloc*8 + nloc
  const ushort_t* gsrc[4];
  int ldst[4];
#pragma unroll
  for (int s = 0; s < 4; ++s) {
    const int u    = wave * 4 + s;
    const int nloc = u & 7;
    const int kloc = u >> 3;
    gsrc[s] = Bp + ((size_t)((tileN >> 4) + nloc) * NKB + kloc) * 512 + lane * 8;
    ldst[s] = u * 512 + lane * 8;
  }

  // x pointers: frag mf covers rows tileM + wm*32 + mf*16 + (lane&15);
  // k-octet (lane>>4) -> i-pair (lane>>4)*2 within each k32 block.
  const float* xptr[2];
#pragma unroll
  for (int mf = 0; mf < 2; ++mf)
    xptr[mf] = x + (size_t)(tileM + wm * 32 + mf * 16 + (lane & 15)) * D_DIM
                 + (lane >> 4) * 2;

  f32x4 acc[2][4];
  const f32x4 zero = {0.0f, 0.0f, 0.0f, 0.0f};
#pragma unroll
  for (int mf = 0; mf < 2; ++mf)
#pragma unroll
    for (int nf = 0; nf < 4; ++nf) acc[mf][nf] = zero;

#define STAGE(bb, it)                                                   \
  do {                                                                  \
    _Pragma("unroll")                                                   \
    for (int s = 0; s < 4; ++s)                                         \
      load_lds16(gsrc[s] + (size_t)(it) * 1024, &lds[bb][ldst[s]]);     \
  } while (0)

  float2 xc[2][2], xn[2][2];
#pragma unroll
  for (int kl = 0; kl < 2; ++kl)
#pragma unroll
    for (int mf = 0; mf < 2; ++mf)
      xc[kl][mf] = *(const float2*)(xptr[mf] + (size_t)kl * 8);

  STAGE(0, 0);
  __syncthreads();   // drain iter-0 DMA

  for (int it = 0; it < 64; ++it) {
    const int cur = it & 1;
    if (it + 1 < 64) {
      STAGE(cur ^ 1, it + 1);   // in flight across this iter's compute
#pragma unroll
      for (int kl = 0; kl < 2; ++kl)
#pragma unroll
        for (int mf = 0; mf < 2; ++mf)
          xn[kl][mf] = *(const float2*)(xptr[mf] + ((size_t)(it + 1) * 2 + kl) * 8);
    }

#pragma unroll
    for (int kl = 0; kl < 2; ++kl) {
      bf16x8 a[2], b[4];
#pragma unroll
      for (int mf = 0; mf < 2; ++mf)
        a[mf] = build_afrag(xc[kl][mf].x, xc[kl][mf].y);
#pragma unroll
      for (int nf = 0; nf < 4; ++nf)
        b[nf] = *(const bf16x8*)&lds[cur][(kl * 8 + wn * 4 + nf) * 512 + lane * 8];
#pragma unroll
      for (int mf = 0; mf < 2; ++mf)
#pragma unroll
        for (int nf = 0; nf < 4; ++nf)
          acc[mf][nf] = __builtin_amdgcn_mfma_f32_16x16x32_bf16(a[mf], b[nf], acc[mf][nf], 0, 0, 0);
    }

#pragma unroll
    for (int kl = 0; kl < 2; ++kl)
#pragma unroll
      for (int mf = 0; mf < 2; ++mf)
        xc[kl][mf] = xn[kl][mf];

    __syncthreads();   // releases cur for overwrite; drains next-iter DMA
  }
#undef STAGE

  // epilogue: C/D map: col = lane&15, row = (lane>>4)*4 + reg
  const int crow0 = tileM + wm * 32 + (lane >> 4) * 4;
  const int ccol0 = tileN + wn * 64 + (lane & 15);
#pragma unroll
  for (int nf = 0; nf < 4; ++nf) {
    const int col = ccol0 + nf * 16;
    float bv = bias[col];
#pragma unroll 8
    for (int g = 0; g < 32; ++g) bv += part[(size_t)g * U_DIM + col];
#pragma unroll
    for (int mf = 0; mf < 2; ++mf) {
#pragma unroll
      for (int r = 0; r < 4; ++r) {
        const int row = crow0 + mf * 16 + r;
        C[(size_t)row * U_DIM + col] = gelu_exact(acc[mf][nf][r] + bv);
      }
    }
  }
}

// ---------------- fallback (ws too small): fp32, no workspace ----------------
__global__ void fallback_kernel(const float* __restrict__ x, const float* __restrict__ W,
                                const float* __restrict__ bias, float* __restrict__ out) {
  int j  = blockIdx.x * 256 + threadIdx.x;
  int b0 = blockIdx.y * 16;
  float acc[16];
#pragma unroll
  for (int t = 0; t < 16; ++t) acc[t] = 0.0f;
  for (int i = 0; i < D_DIM; ++i) {
    const float* wr = W + (size_t)i * 5 * U_DIM + j;
    float w0 = wr[0 * U_DIM], w1 = wr[1 * U_DIM], w2 = wr[2 * U_DIM];
    float w3 = wr[3 * U_DIM], w4 = wr[4 * U_DIM];
#pragma unroll
    for (int t = 0; t < 16; ++t) {
      float xv = x[(size_t)(b0 + t) * D_DIM + i];
      float x2 = xv * xv;
      acc[t] += w0 + xv * w1 + x2 * w2 + x2 * xv * w3 + x2 * x2 * w4;
    }
  }
  float bv = bias[j];
#pragma unroll
  for (int t = 0; t < 16; ++t)
    out[(size_t)(b0 + t) * U_DIM + j] = gelu_exact(acc[t] + bv);
}

extern "C" void kernel_launch(void* const* d_in, const int* in_sizes, int n_in,
                              void* d_out, int out_size, void* d_ws, size_t ws_size,
                              hipStream_t stream) {
  const float* x    = (const float*)d_in[0];   // (4096, 1024)
  const float* W    = (const float*)d_in[1];   // (1024, 5, 1024), row r = i*5+k
  const float* bias = (const float*)d_in[2];   // (1024,)
  float* out = (float*)d_out;                  // (4096, 1024) fp32

  const size_t szB = (size_t)U_DIM * KT2 * sizeof(ushort_t);   // 8.39 MB
  const size_t szP = (size_t)32 * U_DIM * sizeof(float);       // 128 KB

  if (ws_size >= szB + szP) {
    ushort_t* Bp   = (ushort_t*)d_ws;
    float*    part = (float*)((char*)d_ws + szB);
    w_pack_fold_kernel<<<dim3(32, U_DIM / 16), 256, 0, stream>>>(W, Bp, part);
    gemm_kernel<<<dim3(U_DIM / 128, B_DIM / 64), 256, 0, stream>>>(x, Bp, bias, part, out);
  } else {
    fallback_kernel<<<dim3(U_DIM / 256, B_DIM / 16), 256, 0, stream>>>(x, W, bias, out);
  }
}